// Round 6
// baseline (435.870 us; speedup 1.0000x reference)
//
#include <hip/hip_runtime.h>
#include <hip/hip_bf16.h>

typedef __bf16 bf16x8 __attribute__((ext_vector_type(8)));
typedef float f32x4 __attribute__((ext_vector_type(4)));
typedef unsigned short u16;
typedef unsigned int u32;
typedef unsigned long long u64;

// B=32, L=1024, D=1024, H=8, E=128, M=64 modes. M2=128 (re/im interleaved in G2T/OS2T).

static __device__ __forceinline__ u16 f2b(float f) {
  u32 u = __builtin_bit_cast(u32, f);
  u32 r = (u + 0x7FFFu + ((u >> 16) & 1u)) >> 16;
  return (u16)r;
}
static __device__ __forceinline__ u32 pk2(float lo, float hi) {
  return (u32)f2b(lo) | ((u32)f2b(hi) << 16);
}
static __device__ __forceinline__ f32x4 mfma16(bf16x8 a, bf16x8 b, f32x4 c) {
  return __builtin_amdgcn_mfma_f32_16x16x32_bf16(a, b, c, 0, 0, 0);
}

// ---------------- prep: DFT tables (bf16) + Wq/Wo -> bf16 ----------------
__global__ __launch_bounds__(256) void k_prep(
    const float* __restrict__ Wq, const float* __restrict__ Wo,
    u16* __restrict__ FT, u16* __restrict__ FI2,
    u16* __restrict__ Wq16, u16* __restrict__ Wo16) {
  int idx = blockIdx.x * 256 + threadIdx.x;
  const float W0 = 6.283185307179586f / 1024.0f;
  if (idx < 131072) {                       // FT[m2][l]: rfft rows (0..63 re, 64..127 im)
    int m2 = idx >> 10, l = idx & 1023;
    int m = (m2 < 64) ? m2 : (m2 - 64);
    int t = (m * l) & 1023;
    float s, c;
    __sincosf((float)t * W0, &s, &c);
    FT[idx] = f2b((m2 < 64) ? c : -s);
  } else if (idx < 262144) {                // FI2[j][l], j = 2m (+1 for imag)
    int jj = idx - 131072;
    int j = jj >> 10, l = jj & 1023;
    int m = j >> 1;
    int t = (m * l) & 1023;
    float s, c;
    __sincosf((float)t * W0, &s, &c);
    float v;
    if ((j & 1) == 0) v = (m == 0) ? (1.0f / 1024.0f) : c * (2.0f / 1024.0f);
    else              v = (m == 0) ? 0.0f : -s * (2.0f / 1024.0f);
    FI2[jj] = f2b(v);
  } else if (idx < 262144 + 1048576) {
    int k = idx - 262144;
    Wq16[k] = f2b(Wq[k]);
  } else {
    int k = idx - 1310720;
    Wo16[k] = f2b(Wo[k]);
  }
}

// ------------- w1 transpose: [h][e][o][m] f32 -> [h][m][e][o] bf16 -------------
__global__ __launch_bounds__(256) void k_wtrans(
    const float* __restrict__ w1r, const float* __restrict__ w1i,
    u16* __restrict__ W2r, u16* __restrict__ W2i) {
  __shared__ float T[128 * 65];
  int h = blockIdx.x >> 7, e = blockIdx.x & 127;
  int tid = threadIdx.x;
  for (int pass = 0; pass < 2; ++pass) {
    const float* src = pass ? w1i : w1r;
    u16* dst = pass ? W2i : W2r;
    {
      int m = tid & 63, og = tid >> 6;
      const float* sp = src + (((size_t)h * 128 + e) * 128) * 64 + m;
      for (int k = 0; k < 32; ++k) {
        int o = og * 32 + k;
        T[o * 65 + m] = sp[(size_t)o * 64];
      }
    }
    __syncthreads();
    {
      int o = tid & 127, mg = tid >> 7;
      for (int k = 0; k < 32; ++k) {
        int m = mg * 32 + k;
        dst[(((size_t)h * 64 + m) * 128 + e) * 128 + o] = f2b(T[o * 65 + m]);
      }
    }
    __syncthreads();
  }
}

// ----- 128x128-tile bf16 GEMM, register-double-buffered staging (T14) -----
// C = A @ Bm. A row-major (k contig), Bm row-major [k][1024].
// TSTORE: store transposed u64-packed C^T[col][row] (for G2T).
template <int KSTEPS, bool BIAS, bool TSTORE>
static __device__ __forceinline__ void gemm128_db(
    const u16* __restrict__ A, size_t arow0, int astride,
    const u16* __restrict__ Bm, int bcol0,
    u16* __restrict__ C, size_t crow0, const float* __restrict__ bias) {
  __shared__ __align__(16) u16 Al[128 * 40];
  __shared__ __align__(16) u16 Bl[128 * 40];
  int tid = threadIdx.x, lane = tid & 63, w = tid >> 6;
  f32x4 acc[2][8];
#pragma unroll
  for (int i = 0; i < 2; i++)
#pragma unroll
    for (int j = 0; j < 8; j++) acc[i][j] = (f32x4){0.f, 0.f, 0.f, 0.f};
  int ar = tid >> 1, ahalf = tid & 1;
  int dloc = tid & 127, lg = tid >> 7;
  const u16* aptr = A + (arow0 + ar) * (size_t)astride + ahalf * 16;
  const u16* bptr = Bm + (size_t)(lg * 16) * 1024 + bcol0 + dloc;
  uint4 av0, av1;
  u16 bs[16];
  av0 = *(const uint4*)aptr;
  av1 = *(const uint4*)(aptr + 8);
#pragma unroll
  for (int jj = 0; jj < 4; ++jj) {
    const u16* bp = bptr + (size_t)(jj * 4) * 1024;
    bs[jj * 4 + 0] = bp[0]; bs[jj * 4 + 1] = bp[1024];
    bs[jj * 4 + 2] = bp[2048]; bs[jj * 4 + 3] = bp[3072];
  }
  for (int kk = 0; kk < KSTEPS; ++kk) {
    {
      uint4* dst = (uint4*)(Al + ar * 40 + ahalf * 16);
      dst[0] = av0; dst[1] = av1;
    }
#pragma unroll
    for (int jj = 0; jj < 4; ++jj) {
      int l0 = lg * 16 + jj * 4;
      *(u64*)(Bl + dloc * 40 + l0) = (u64)bs[jj * 4] | ((u64)bs[jj * 4 + 1] << 16) |
                                     ((u64)bs[jj * 4 + 2] << 32) | ((u64)bs[jj * 4 + 3] << 48);
    }
    __syncthreads();
    if (kk + 1 < KSTEPS) {  // issue next-tile loads; consumed at next ds_write
      const u16* ap = aptr + (kk + 1) * 32;
      av0 = *(const uint4*)ap;
      av1 = *(const uint4*)(ap + 8);
      const u16* bk = bptr + (size_t)((kk + 1) * 32) * 1024;
#pragma unroll
      for (int jj = 0; jj < 4; ++jj) {
        const u16* bp = bk + (size_t)(jj * 4) * 1024;
        bs[jj * 4 + 0] = bp[0]; bs[jj * 4 + 1] = bp[1024];
        bs[jj * 4 + 2] = bp[2048]; bs[jj * 4 + 3] = bp[3072];
      }
    }
    bf16x8 af[2];
#pragma unroll
    for (int mi = 0; mi < 2; mi++)
      af[mi] = *(const bf16x8*)(Al + (w * 32 + mi * 16 + (lane & 15)) * 40 + 8 * (lane >> 4));
#pragma unroll
    for (int ni = 0; ni < 8; ni++) {
      bf16x8 bf = *(const bf16x8*)(Bl + (ni * 16 + (lane & 15)) * 40 + 8 * (lane >> 4));
#pragma unroll
      for (int mi = 0; mi < 2; mi++) acc[mi][ni] = mfma16(af[mi], bf, acc[mi][ni]);
    }
    __syncthreads();
  }
  if (BIAS) {  // += L*bq on local row 0 (mode-0 real row of XF)
    if (w == 0 && (lane >> 4) == 0) {
#pragma unroll
      for (int ni = 0; ni < 8; ni++)
        acc[0][ni][0] += 1024.0f * bias[bcol0 + ni * 16 + (lane & 15)];
    }
  }
  if (TSTORE) {
#pragma unroll
    for (int mi = 0; mi < 2; mi++)
#pragma unroll
      for (int ni = 0; ni < 8; ni++) {
        int row0 = w * 32 + mi * 16 + 4 * (lane >> 4);
        int col = bcol0 + ni * 16 + (lane & 15);
        u64 pk = (u64)f2b(acc[mi][ni][0]) | ((u64)f2b(acc[mi][ni][1]) << 16) |
                 ((u64)f2b(acc[mi][ni][2]) << 32) | ((u64)f2b(acc[mi][ni][3]) << 48);
        *(u64*)(C + (size_t)col * 128 + row0) = pk;
      }
  } else {
#pragma unroll
    for (int mi = 0; mi < 2; mi++)
#pragma unroll
      for (int ni = 0; ni < 8; ni++)
#pragma unroll
        for (int r = 0; r < 4; r++) {
          int row = w * 32 + mi * 16 + 4 * (lane >> 4) + r;
          int col = bcol0 + ni * 16 + (lane & 15);
          C[(crow0 + row) * (size_t)1024 + col] = f2b(acc[mi][ni][r]);
        }
  }
}

// -------- DFT: Z[b][m2][c] = sum_l FT[m2][l]*x[b][l][c], reg-dbuf f32 loader --------
__global__ __launch_bounds__(256) void k_dft(const float* __restrict__ x,
                                             const u16* __restrict__ FT,
                                             u16* __restrict__ Z) {
  __shared__ __align__(16) u16 Al[128 * 40];
  __shared__ __align__(16) u16 Bl[128 * 40];
  int b = blockIdx.x >> 3, ct = blockIdx.x & 7;
  int tid = threadIdx.x, lane = tid & 63, w = tid >> 6;
  f32x4 acc[2][8];
#pragma unroll
  for (int i = 0; i < 2; i++)
#pragma unroll
    for (int j = 0; j < 8; j++) acc[i][j] = (f32x4){0.f, 0.f, 0.f, 0.f};
  int ar = tid >> 1, ahalf = tid & 1;
  int c = tid & 127, lg = tid >> 7;
  const u16* aptr = FT + ar * 1024 + ahalf * 16;
  const float* bbase = x + ((size_t)b * 1024) * 1024 + ct * 128 + c;
  uint4 av0, av1;
  float bx[16];
  av0 = *(const uint4*)aptr;
  av1 = *(const uint4*)(aptr + 8);
#pragma unroll
  for (int jj = 0; jj < 4; ++jj) {
    const float* bp = bbase + (size_t)(lg * 16 + jj * 4) * 1024;
    bx[jj * 4 + 0] = bp[0]; bx[jj * 4 + 1] = bp[1024];
    bx[jj * 4 + 2] = bp[2048]; bx[jj * 4 + 3] = bp[3072];
  }
  for (int kk = 0; kk < 32; ++kk) {
    {
      uint4* dst = (uint4*)(Al + ar * 40 + ahalf * 16);
      dst[0] = av0; dst[1] = av1;
    }
#pragma unroll
    for (int jj = 0; jj < 4; ++jj) {
      uint2 p = {pk2(bx[jj * 4], bx[jj * 4 + 1]), pk2(bx[jj * 4 + 2], bx[jj * 4 + 3])};
      *(uint2*)(Bl + c * 40 + lg * 16 + jj * 4) = p;
    }
    __syncthreads();
    if (kk < 31) {
      const u16* ap = aptr + (kk + 1) * 32;
      av0 = *(const uint4*)ap;
      av1 = *(const uint4*)(ap + 8);
      const float* bk = bbase + (size_t)((kk + 1) * 32) * 1024;
#pragma unroll
      for (int jj = 0; jj < 4; ++jj) {
        const float* bp = bk + (size_t)(jj * 4) * 1024;
        bx[jj * 4 + 0] = bp[0]; bx[jj * 4 + 1] = bp[1024];
        bx[jj * 4 + 2] = bp[2048]; bx[jj * 4 + 3] = bp[3072];
      }
    }
    bf16x8 af[2];
#pragma unroll
    for (int mi = 0; mi < 2; mi++)
      af[mi] = *(const bf16x8*)(Al + (w * 32 + mi * 16 + (lane & 15)) * 40 + 8 * (lane >> 4));
#pragma unroll
    for (int ni = 0; ni < 8; ni++) {
      bf16x8 bf = *(const bf16x8*)(Bl + (ni * 16 + (lane & 15)) * 40 + 8 * (lane >> 4));
#pragma unroll
      for (int mi = 0; mi < 2; mi++) acc[mi][ni] = mfma16(af[mi], bf, acc[mi][ni]);
    }
    __syncthreads();
  }
#pragma unroll
  for (int mi = 0; mi < 2; mi++)
#pragma unroll
    for (int ni = 0; ni < 8; ni++)
#pragma unroll
      for (int r = 0; r < 4; r++) {
        int row = w * 32 + mi * 16 + 4 * (lane >> 4) + r;
        int col = ct * 128 + ni * 16 + (lane & 15);
        Z[((size_t)b * 128 + row) * 1024 + col] = f2b(acc[mi][ni][r]);
      }
}

__global__ __launch_bounds__(256) void k_wqmix(const u16* __restrict__ Zm,
                                               const u16* __restrict__ Wq16,
                                               const float* __restrict__ bq,
                                               u16* __restrict__ XF) {
  int mt = blockIdx.x >> 3, nt = blockIdx.x & 7;
  gemm128_db<32, true, false>(Zm, (size_t)mt * 128, 1024, Wq16, nt * 128, XF,
                              (size_t)mt * 128, bq);
}

// G2T[d][j] = (FI2 @ Wo16)^T : transposed for direct frag loads in k_nxdecomp
__global__ __launch_bounds__(256) void k_gmat(const u16* __restrict__ FI2,
                                              const u16* __restrict__ Wo16,
                                              u16* __restrict__ G2T) {
  int nt = blockIdx.x;
  gemm128_db<32, false, true>(FI2, 0, 1024, Wo16, nt * 128, G2T, 0, nullptr);
}

// ------- mode mix per (h,m): complex [32b x 128e] @ [128e x 128o] -> OS2T -------
// XA frags direct from XF (16B contiguous); W staged to LDS, reg-double-buffered.
__global__ __launch_bounds__(256) void k_modemix(const u16* __restrict__ XF,
                                                 const u16* __restrict__ W2r,
                                                 const u16* __restrict__ W2i,
                                                 u16* __restrict__ OS2T) {
  __shared__ __align__(16) u16 Wbr[128 * 40], Wbi[128 * 40];
  int h = blockIdx.x >> 6, m = blockIdx.x & 63;
  int tid = threadIdx.x, lane = tid & 63, w = tid >> 6;
  // prefetch all XA frags (re/im, 2 mi x 4 kk) upfront
  bf16x8 xar[2][4], xai[2][4];
#pragma unroll
  for (int mi = 0; mi < 2; ++mi) {
    int bb = mi * 16 + (lane & 15);
    const u16* xr = XF + ((size_t)(bb * 128 + m)) * 1024 + h * 128 + 8 * (lane >> 4);
    const u16* xi = XF + ((size_t)(bb * 128 + 64 + m)) * 1024 + h * 128 + 8 * (lane >> 4);
#pragma unroll
    for (int kk = 0; kk < 4; ++kk) {
      xar[mi][kk] = *(const bf16x8*)(xr + kk * 32);
      xai[mi][kk] = *(const bf16x8*)(xi + kk * 32);
    }
  }
  // W loader (reg dbuf)
  int o = tid & 127, pr = tid >> 7;
  const u16* wsrc = (pr ? W2i : W2r) + ((size_t)(h * 64 + m) * 128) * 128 + o;
  u16 ws_[32];
#pragma unroll
  for (int e = 0; e < 32; ++e) ws_[e] = wsrc[(size_t)e * 128];
  f32x4 accR[2][2], accI[2][2];
#pragma unroll
  for (int i = 0; i < 2; i++)
#pragma unroll
    for (int j = 0; j < 2; j++) {
      accR[i][j] = (f32x4){0.f, 0.f, 0.f, 0.f};
      accI[i][j] = (f32x4){0.f, 0.f, 0.f, 0.f};
    }
  for (int kk = 0; kk < 4; ++kk) {
    {
      u16* wdst = (pr ? Wbi : Wbr) + o * 40;
#pragma unroll
      for (int jj = 0; jj < 8; ++jj)
        *(u64*)(wdst + jj * 4) = (u64)ws_[jj * 4] | ((u64)ws_[jj * 4 + 1] << 16) |
                                 ((u64)ws_[jj * 4 + 2] << 32) | ((u64)ws_[jj * 4 + 3] << 48);
    }
    __syncthreads();
    if (kk < 3) {
      const u16* wk = wsrc + (size_t)((kk + 1) * 32) * 128;
#pragma unroll
      for (int e = 0; e < 32; ++e) ws_[e] = wk[(size_t)e * 128];
    }
    bf16x8 ain[2];
#pragma unroll
    for (int mi = 0; mi < 2; mi++) {
      u32 t4[4];
      __builtin_memcpy(t4, &xai[mi][kk], 16);
#pragma unroll
      for (int q = 0; q < 4; q++) t4[q] ^= 0x80008000u;
      __builtin_memcpy(&ain[mi], t4, 16);
    }
#pragma unroll
    for (int ni = 0; ni < 2; ni++) {
      int o2 = w * 32 + ni * 16 + (lane & 15);
      bf16x8 br = *(const bf16x8*)(Wbr + o2 * 40 + 8 * (lane >> 4));
      bf16x8 bi = *(const bf16x8*)(Wbi + o2 * 40 + 8 * (lane >> 4));
#pragma unroll
      for (int mi = 0; mi < 2; mi++) {
        accR[mi][ni] = mfma16(xar[mi][kk], br, accR[mi][ni]);
        accR[mi][ni] = mfma16(ain[mi], bi, accR[mi][ni]);
        accI[mi][ni] = mfma16(xar[mi][kk], bi, accI[mi][ni]);
        accI[mi][ni] = mfma16(xai[mi][kk], br, accI[mi][ni]);
      }
    }
    __syncthreads();
  }
#pragma unroll
  for (int mi = 0; mi < 2; mi++)
#pragma unroll
    for (int ni = 0; ni < 2; ni++)
#pragma unroll
      for (int rr = 0; rr < 4; rr++) {
        int brow = mi * 16 + 4 * (lane >> 4) + rr;
        int o3 = w * 32 + ni * 16 + (lane & 15);
        size_t base = (size_t)brow * 131072 + (size_t)(h * 128 + o3) * 128;
        *(u32*)(OS2T + base + 2 * m) = pk2(accR[mi][ni][rr], accI[mi][ni][rr]);
      }
}

// ---- fused output GEMM + residual + series_decomp (direct-frag, LDS = ZT only) ----
__global__ __launch_bounds__(256) void k_nxdecomp(const float* __restrict__ x,
                                                  const u16* __restrict__ OS2T,
                                                  const u16* __restrict__ G2T,
                                                  float* __restrict__ out) {
  __shared__ float ZT[160 * 68];  // 43520 B -> 3 blocks/CU
  int bid = blockIdx.x;
  // XCD grouping: 16 dt-blocks sharing OS2T rows have bid % 8 == rt -> same XCD
  int rt = bid & 7, dt = (bid >> 3) & 15, b = bid >> 7;
  int r0 = rt * 128, d0 = dt * 64;
  int tid = threadIdx.x, lane = tid & 63, w = tid >> 6;
  int wr = w >> 1, wc = w & 1;
  // A/B frag pointers (k contiguous in both OS2T and G2T)
  const u16* pA[5];
#pragma unroll
  for (int mi = 0; mi < 5; ++mi) {
    int row = wr * 80 + mi * 16 + (lane & 15);
    int gr = r0 - 16 + row;
    gr = gr < 0 ? 0 : (gr > 1023 ? 1023 : gr);
    pA[mi] = OS2T + ((size_t)b * 1024 + gr) * 128 + 8 * (lane >> 4);
  }
  const u16* pB[2];
#pragma unroll
  for (int ni = 0; ni < 2; ++ni) {
    int col = d0 + wc * 32 + ni * 16 + (lane & 15);
    pB[ni] = G2T + (size_t)col * 128 + 8 * (lane >> 4);
  }
  f32x4 acc[5][2];
#pragma unroll
  for (int i = 0; i < 5; i++)
#pragma unroll
    for (int j = 0; j < 2; j++) acc[i][j] = (f32x4){0.f, 0.f, 0.f, 0.f};
  // 2-stage register pipeline over kk
  bf16x8 aC[5], bC[2], aN[5], bN[2];
#pragma unroll
  for (int i = 0; i < 5; ++i) aC[i] = *(const bf16x8*)(pA[i]);
#pragma unroll
  for (int i = 0; i < 2; ++i) bC[i] = *(const bf16x8*)(pB[i]);
#pragma unroll
  for (int kk = 0; kk < 4; ++kk) {
    if (kk < 3) {
#pragma unroll
      for (int i = 0; i < 5; ++i) aN[i] = *(const bf16x8*)(pA[i] + (kk + 1) * 32);
#pragma unroll
      for (int i = 0; i < 2; ++i) bN[i] = *(const bf16x8*)(pB[i] + (kk + 1) * 32);
    }
#pragma unroll
    for (int mi = 0; mi < 5; ++mi)
#pragma unroll
      for (int ni = 0; ni < 2; ++ni) acc[mi][ni] = mfma16(aC[mi], bC[ni], acc[mi][ni]);
    if (kk < 3) {
#pragma unroll
      for (int i = 0; i < 5; ++i) aC[i] = aN[i];
#pragma unroll
      for (int i = 0; i < 2; ++i) bC[i] = bN[i];
    }
  }
  // z = GEMM + x into ZT
#pragma unroll
  for (int mi = 0; mi < 5; ++mi)
#pragma unroll
    for (int r = 0; r < 4; ++r) {
      int row = wr * 80 + mi * 16 + 4 * (lane >> 4) + r;
      int gr = r0 - 16 + row;
      gr = gr < 0 ? 0 : (gr > 1023 ? 1023 : gr);
      const float* xp = x + ((size_t)b * 1024 + gr) * 1024 + d0;
#pragma unroll
      for (int ni = 0; ni < 2; ++ni) {
        int col = wc * 32 + ni * 16 + (lane & 15);
        ZT[row * 68 + col] = acc[mi][ni][r] + xp[col];
      }
    }
  __syncthreads();
  {
    int c = tid & 63, h2 = tid >> 6;
    int j0 = h2 * 32;
    float s = 0.f;
#pragma unroll
    for (int u = 0; u < 25; ++u) s += ZT[(j0 + 4 + u) * 68 + c];
    for (int j = j0; j < j0 + 32; ++j) {
      float center = ZT[(j + 16) * 68 + c];
      out[((size_t)b * 1024 + r0 + j) * 1024 + d0 + c] = center - s * (1.0f / 25.0f);
      if (j < j0 + 31) s += ZT[(j + 29) * 68 + c] - ZT[(j + 4) * 68 + c];
    }
  }
}

extern "C" void kernel_launch(void* const* d_in, const int* in_sizes, int n_in,
                              void* d_out, int out_size, void* d_ws, size_t ws_size,
                              hipStream_t stream) {
  const float* x = (const float*)d_in[0];
  const float* Wq = (const float*)d_in[1];
  const float* bq = (const float*)d_in[2];
  const float* w1r = (const float*)d_in[3];
  const float* w1i = (const float*)d_in[4];
  const float* Wo = (const float*)d_in[5];
  // d_in[6] = bo: cancels exactly in res = z - MA(z) (constant along L, replicate pad)

  char* ws = (char*)d_ws;
  u16* FT = (u16*)(ws + 0x000000);     // 256 KB [128][1024]
  u16* FI2 = (u16*)(ws + 0x040000);    // 256 KB [128][1024] interleaved rows
  u16* Wq16 = (u16*)(ws + 0x080000);   // 2 MB
  u16* Wo16 = (u16*)(ws + 0x280000);   // 2 MB
  u16* G2T = (u16*)(ws + 0x480000);    // 256 KB [1024 d][128 j]
  u16* OS2T = (u16*)(ws + 0x4C0000);   // 8.4 MB [b][i'][m2-interleaved]

  // Scratch dead before k_nxdecomp lives in d_out (fully rewritten at the end)
  char* ob = (char*)d_out;
  u16* W2r = (u16*)(ob + 0x0000000);   // 16.8 MB [h][m][e][o]
  u16* W2i = (u16*)(ob + 0x1000000);   // 16.8 MB
  u16* Zm = (u16*)(ob + 0x2000000);    // 8.4 MB [b][m2][1024]
  u16* XF = (u16*)(ob + 0x2800000);    // 8.4 MB [b*128+m2][1024]

  k_prep<<<9216, 256, 0, stream>>>(Wq, Wo, FT, FI2, Wq16, Wo16);
  k_wtrans<<<1024, 256, 0, stream>>>(w1r, w1i, W2r, W2i);
  k_gmat<<<8, 256, 0, stream>>>(FI2, Wo16, G2T);
  k_dft<<<256, 256, 0, stream>>>(x, FT, Zm);
  k_wqmix<<<256, 256, 0, stream>>>(Zm, Wq16, bq, XF);
  k_modemix<<<512, 256, 0, stream>>>(XF, W2r, W2i, OS2T);
  k_nxdecomp<<<4096, 256, 0, stream>>>(x, OS2T, G2T, (float*)d_out);
}